// Round 7
// baseline (772.787 us; speedup 1.0000x reference)
//
#include <hip/hip_runtime.h>
#include <cmath>

#define N_TOK 8192
#define DIM 1024

using bf16x8 = __attribute__((ext_vector_type(8))) short;
using f32x4  = __attribute__((ext_vector_type(4))) float;

__device__ __forceinline__ unsigned f2bf(float f) {
  unsigned u = __float_as_uint(f);
  return (u + 0x7fffu + ((u >> 16) & 1u)) >> 16;
}

__global__ __launch_bounds__(1024) void k_setup(const int* __restrict__ tgt,
                                                int* __restrict__ cnt,
                                                int* __restrict__ hoff,
                                                int* __restrict__ perm) {
  __shared__ int base[3];
  int t = threadIdx.x;
  if (t < 3) base[t] = 0;
  __syncthreads();
  for (int i = t; i < N_TOK; i += 1024) {
    int tg = tgt[i];
    int cid = (tg < 10000) ? 0 : (tg < 30000 ? 1 : 2);
    int slot = atomicAdd(&base[cid], 1);
    perm[cid * N_TOK + slot] = i;
  }
  __syncthreads();
  if (t < 3) cnt[t] = base[t];
  if (t == 0) {
    hoff[0] = 0;
    hoff[1] = base[0] * 1024;
    hoff[2] = base[0] * 1024 + base[1] * 512;
  }
}

// ---------------- hidden GEMM core: barrier-free fragment-direct ----------
// 128 tokens x 128 dims per block; wave tile 64x64; A=x fp32, B=P fp32,
// packed to bf16 in-register via v_perm (truncation). No K-loop barriers.
template<int PD>
__device__ __forceinline__ void hid_core(
    const float* __restrict__ x, const float* __restrict__ P,
    const int* __restrict__ perm_c, int count, int row0, int dim0,
    unsigned short* __restrict__ hb_c, int* ptoks, short* Os) {
  const int t = threadIdx.x, wv = t >> 6, lane = t & 63, m = lane & 15, q = lane >> 4;
  const int wr = wv >> 1, wc = wv & 1;
  if (t < 128) {
    int idx = row0 + t;
    ptoks[t] = perm_c[min(idx, count - 1)];
  }
  __syncthreads();

  const float* aP[4];
  const float* bP[4];
  #pragma unroll
  for (int i = 0; i < 4; ++i) {
    aP[i] = x + (size_t)ptoks[wr * 64 + i * 16 + m] * DIM + q * 8;
    bP[i] = P + (size_t)(dim0 + wc * 64 + i * 16 + m) * DIM + q * 8;
  }

  f32x4 acc[4][4];
  #pragma unroll
  for (int rt = 0; rt < 4; ++rt)
    #pragma unroll
    for (int ct = 0; ct < 4; ++ct) acc[rt][ct] = (f32x4){0.f, 0.f, 0.f, 0.f};

  #pragma unroll 2
  for (int k0 = 0; k0 < DIM; k0 += 32) {
    union { bf16x8 v; unsigned u[4]; } af[4], bf_[4];
    #pragma unroll
    for (int i = 0; i < 4; ++i) {
      uint4 a0 = *(const uint4*)(aP[i] + k0);
      uint4 a1 = *(const uint4*)(aP[i] + k0 + 4);
      af[i].u[0] = __builtin_amdgcn_perm(a0.y, a0.x, 0x07060302u);
      af[i].u[1] = __builtin_amdgcn_perm(a0.w, a0.z, 0x07060302u);
      af[i].u[2] = __builtin_amdgcn_perm(a1.y, a1.x, 0x07060302u);
      af[i].u[3] = __builtin_amdgcn_perm(a1.w, a1.z, 0x07060302u);
      uint4 b0 = *(const uint4*)(bP[i] + k0);
      uint4 b1 = *(const uint4*)(bP[i] + k0 + 4);
      bf_[i].u[0] = __builtin_amdgcn_perm(b0.y, b0.x, 0x07060302u);
      bf_[i].u[1] = __builtin_amdgcn_perm(b0.w, b0.z, 0x07060302u);
      bf_[i].u[2] = __builtin_amdgcn_perm(b1.y, b1.x, 0x07060302u);
      bf_[i].u[3] = __builtin_amdgcn_perm(b1.w, b1.z, 0x07060302u);
    }
    #pragma unroll
    for (int ct = 0; ct < 4; ++ct)
      #pragma unroll
      for (int rt = 0; rt < 4; ++rt)
        acc[rt][ct] = __builtin_amdgcn_mfma_f32_16x16x32_bf16(af[rt].v, bf_[ct].v,
                                                              acc[rt][ct], 0, 0, 0);
  }

  __syncthreads();
  #pragma unroll
  for (int rt = 0; rt < 4; ++rt)
    #pragma unroll
    for (int ct = 0; ct < 4; ++ct)
      #pragma unroll
      for (int rr = 0; rr < 4; ++rr)
        Os[(wr * 64 + rt * 16 + q * 4 + rr) * 136 + wc * 64 + ct * 16 + m] =
            (short)f2bf(acc[rt][ct][rr]);
  __syncthreads();
  {
    int orow = t >> 1, oh = t & 1;
    int slot = row0 + orow;
    if (slot < count) {
      unsigned short* dst = hb_c + (size_t)slot * PD + dim0 + oh * 64;
      const short* src = &Os[orow * 136 + oh * 64];
      #pragma unroll
      for (int i = 0; i < 8; ++i)
        *(uint4*)(dst + i * 8) = *(const uint4*)(src + i * 8);
    }
  }
}

// Fused: z==0 -> W fp32->bf16 conversion (HBM-bound);
//        z==1..3 -> hidden GEMM for cid=z-1. Co-scheduled.
__global__ __launch_bounds__(256, 3) void k_hc(
    const float* __restrict__ x,
    const float* __restrict__ p0, const float* __restrict__ p1, const float* __restrict__ p2,
    const float* __restrict__ w0, const float* __restrict__ w1, const float* __restrict__ w2,
    const int* __restrict__ perm, const int* __restrict__ cnt, const int* __restrict__ hoffs,
    unsigned short* __restrict__ wb, unsigned short* __restrict__ hb) {
  if (blockIdx.z == 0) {
    const int nw0 = 10240000, nw1 = 10240000, nw2 = 5185792;
    const int total4 = (nw0 + nw1 + nw2) >> 2;
    for (int i = blockIdx.x * 256 + threadIdx.x; i < total4; i += 512 * 256) {
      int e = i << 2;
      const float* src;
      if (e < nw0) src = w0 + e;
      else if (e < nw0 + nw1) src = w1 + (e - nw0);
      else src = w2 + (e - nw0 - nw1);
      float4 v = *(const float4*)src;
      uint2 o;
      o.x = f2bf(v.x) | (f2bf(v.y) << 16);
      o.y = f2bf(v.z) | (f2bf(v.w) << 16);
      *(uint2*)(wb + e) = o;
    }
    return;
  }
  const int cid = blockIdx.z - 1;
  const int pd = (cid == 0) ? 1024 : (cid == 1) ? 512 : 256;
  const int count = cnt[cid];
  if (count == 0) return;
  const int nchd = pd >> 7;
  const int chunk = blockIdx.x % nchd;
  const int tile = blockIdx.x / nchd;
  if (tile * 128 >= count) return;
  const int dim0 = chunk * 128, row0 = tile * 128;
  const float* P = (cid == 0) ? p0 : (cid == 1) ? p1 : p2;
  unsigned short* hb_c = hb + hoffs[cid];
  const int* perm_c = perm + cid * N_TOK;

  __shared__ int ptoks[128];
  __shared__ short Os[128 * 136];

  if (cid == 0)      hid_core<1024>(x, P, perm_c, count, row0, dim0, hb_c, ptoks, Os);
  else if (cid == 1) hid_core<512>(x, P, perm_c, count, row0, dim0, hb_c, ptoks, Os);
  else               hid_core<256>(x, P, perm_c, count, row0, dim0, hb_c, ptoks, Os);
}

// ---------------- lse core: barrier-free fragment-direct GEMM -------------
// 128 tok x 128 col per block; wave tile 64x64; A,B bf16 fragments loaded
// directly global->VGPR (L2-resident); zero K-loop barriers.
template<int PD>
__device__ __forceinline__ void lse_core(
    const unsigned short* __restrict__ hb_c, const unsigned short* __restrict__ wb_c,
    const float* __restrict__ bias, const int* __restrict__ tgt,
    const int* __restrict__ perm_c, int count, int csize, int cstart,
    int row0, int col0,
    float* __restrict__ psum, float* __restrict__ tlog,
    int* ptoks, int* tlocs) {
  const int t = threadIdx.x, wv = t >> 6, lane = t & 63, m = lane & 15, q = lane >> 4;
  const int wr = wv >> 1, wc = wv & 1;
  if (t < 128) {
    int idx = row0 + t;
    int tok = perm_c[min(idx, count - 1)];
    ptoks[t] = tok;
    tlocs[t] = tgt[tok] - cstart;
  }
  __syncthreads();

  const unsigned short* aP[4];
  const unsigned short* bP[4];
  #pragma unroll
  for (int i = 0; i < 4; ++i) {
    int ra = min(row0 + wr * 64 + i * 16 + m, count - 1);
    aP[i] = hb_c + (size_t)ra * PD + q * 8;
    int cb = min(col0 + wc * 64 + i * 16 + m, csize - 1);
    bP[i] = wb_c + (size_t)cb * PD + q * 8;
  }

  float bc[4];
  #pragma unroll
  for (int ct = 0; ct < 4; ++ct)
    bc[ct] = bias[min(col0 + wc * 64 + ct * 16 + m, csize - 1)];

  f32x4 acc[4][4];
  #pragma unroll
  for (int rt = 0; rt < 4; ++rt)
    #pragma unroll
    for (int ct = 0; ct < 4; ++ct) acc[rt][ct] = (f32x4){0.f, 0.f, 0.f, 0.f};

  #pragma unroll 4
  for (int k0 = 0; k0 < PD; k0 += 32) {
    bf16x8 af[4], bf_[4];
    #pragma unroll
    for (int i = 0; i < 4; ++i) {
      af[i] = *(const bf16x8*)(aP[i] + k0);
      bf_[i] = *(const bf16x8*)(bP[i] + k0);
    }
    #pragma unroll
    for (int ct = 0; ct < 4; ++ct)
      #pragma unroll
      for (int rt = 0; rt < 4; ++rt)
        acc[rt][ct] = __builtin_amdgcn_mfma_f32_16x16x32_bf16(af[rt], bf_[ct],
                                                              acc[rt][ct], 0, 0, 0);
  }

  float run[4][4] = {{0.f}}, tcap[4][4] = {{0.f}};
  int tfnd[4][4] = {{0}};
  int tl[4][4];
  #pragma unroll
  for (int rt = 0; rt < 4; ++rt)
    #pragma unroll
    for (int rr = 0; rr < 4; ++rr)
      tl[rt][rr] = tlocs[wr * 64 + rt * 16 + q * 4 + rr];

  #pragma unroll
  for (int ct = 0; ct < 4; ++ct) {
    int colg = col0 + wc * 64 + ct * 16 + m;
    bool cok = colg < csize;
    #pragma unroll
    for (int rt = 0; rt < 4; ++rt)
      #pragma unroll
      for (int rr = 0; rr < 4; ++rr) {
        float val = acc[rt][ct][rr] + bc[ct];
        if (cok) {
          run[rt][rr] += __expf(val);
          if (tl[rt][rr] == colg) { tcap[rt][rr] = val; tfnd[rt][rr] = 1; }
        }
      }
  }

  #pragma unroll
  for (int rt = 0; rt < 4; ++rt)
    #pragma unroll
    for (int rr = 0; rr < 4; ++rr) {
      float v = run[rt][rr];
      v += __shfl_xor(v, 1, 64);
      v += __shfl_xor(v, 2, 64);
      v += __shfl_xor(v, 4, 64);
      v += __shfl_xor(v, 8, 64);
      int rowl = wr * 64 + rt * 16 + q * 4 + rr;
      if (row0 + rowl < count) {
        int tok = ptoks[rowl];
        if (m == 0) atomicAdd(&psum[tok], v);
        if (tfnd[rt][rr]) tlog[tok] = tcap[rt][rr];
      }
    }
}

__global__ __launch_bounds__(256, 3) void k_lse(
    const unsigned short* __restrict__ hb, const unsigned short* __restrict__ wb,
    const float* __restrict__ b0_, const float* __restrict__ b1_, const float* __restrict__ b2_,
    const int* __restrict__ tgt, const int* __restrict__ perm,
    const int* __restrict__ cnt, const int* __restrict__ hoffs,
    float* __restrict__ psum, float* __restrict__ tlog) {
  const int cid = blockIdx.z;
  const int cstart = (cid == 0) ? 0     : (cid == 1) ? 10000 : 30000;
  const int csize  = (cid == 0) ? 10000 : (cid == 1) ? 20000 : 20257;
  const size_t woff = (cid == 0) ? 0 : (cid == 1) ? (size_t)10240000 : (size_t)20480000;
  const float* bias = (cid == 0) ? b0_ : (cid == 1) ? b1_ : b2_;
  const int count = cnt[cid];
  if (count == 0) return;
  const unsigned ntile = (unsigned)(count + 127) >> 7;
  const int nchunk = (csize + 127) >> 7;
  const int cpx = (nchunk + 7) >> 3;

  // XCD-locality remap: id%8 owns a contiguous chunk range.
  const unsigned d = blockIdx.x;
  const int x8 = d & 7;
  const unsigned g = d >> 3;
  const unsigned ci = g / ntile;
  if (ci >= (unsigned)cpx) return;
  const int chunk = x8 * cpx + (int)ci;
  if (chunk >= nchunk) return;
  const int tile = (int)(g - ci * ntile);
  const int col0 = chunk * 128, row0 = tile * 128;

  const unsigned short* hb_c = hb + hoffs[cid];
  const unsigned short* wb_c = wb + woff;
  const int* perm_c = perm + cid * N_TOK;

  __shared__ int ptoks[128];
  __shared__ int tlocs[128];

  if (cid == 0)
    lse_core<1024>(hb_c, wb_c, bias, tgt, perm_c, count, csize, cstart, row0, col0,
                   psum, tlog, ptoks, tlocs);
  else if (cid == 1)
    lse_core<512>(hb_c, wb_c, bias, tgt, perm_c, count, csize, cstart, row0, col0,
                  psum, tlog, ptoks, tlocs);
  else
    lse_core<256>(hb_c, wb_c, bias, tgt, perm_c, count, csize, cstart, row0, col0,
                  psum, tlog, ptoks, tlocs);
}

__global__ __launch_bounds__(1024) void k_final(const float* __restrict__ psum,
                                                const float* __restrict__ tlog,
                                                float* __restrict__ out) {
  __shared__ float part[16];
  int t = threadIdx.x;
  float s = 0.f;
  for (int n = t; n < N_TOK; n += 1024) {
    float v = __logf(psum[n]) - tlog[n];
    out[1 + n] = v;
    s += v;
  }
  #pragma unroll
  for (int off = 32; off > 0; off >>= 1) s += __shfl_down(s, off, 64);
  if ((t & 63) == 0) part[t >> 6] = s;
  __syncthreads();
  if (t < 64) {
    float v = (t < 16) ? part[t] : 0.f;
    #pragma unroll
    for (int off = 8; off > 0; off >>= 1) v += __shfl_down(v, off, 64);
    if (t == 0) out[0] = v;
  }
}

extern "C" void kernel_launch(void* const* d_in, const int* in_sizes, int n_in,
                              void* d_out, int out_size, void* d_ws, size_t ws_size,
                              hipStream_t stream) {
  const float* x  = (const float*)d_in[0];
  const int* tgt  = (const int*)d_in[1];
  const float* p0 = (const float*)d_in[2];
  const float* w0 = (const float*)d_in[3];
  const float* b0 = (const float*)d_in[4];
  const float* p1 = (const float*)d_in[5];
  const float* w1 = (const float*)d_in[6];
  const float* b1 = (const float*)d_in[7];
  const float* p2 = (const float*)d_in[8];
  const float* w2 = (const float*)d_in[9];
  const float* b2 = (const float*)d_in[10];
  float* out = (float*)d_out;

  char* ws = (char*)d_ws;
  int* cnt            = (int*)(ws + 0);
  int* hoff           = (int*)(ws + 64);
  int* perm           = (int*)(ws + 256);                 // 98,304 B
  unsigned short* wb  = (unsigned short*)(ws + 131072);   // 51,331,584 B
  unsigned short* hb  = (unsigned short*)(ws + 51462656); // 16,777,216 B
  float* psum         = (float*)(ws + 68239872);          // 32,768 B
  float* tlog         = (float*)(ws + 68272640);          // 32,768 B

  hipMemsetAsync(psum, 0, N_TOK * sizeof(float), stream);
  k_setup<<<dim3(1), dim3(1024), 0, stream>>>(tgt, cnt, hoff, perm);
  k_hc<<<dim3(512, 1, 4), dim3(256), 0, stream>>>(x, p0, p1, p2, w0, w1, w2,
                                                  perm, cnt, hoff, wb, hb);
  k_lse<<<dim3(10240, 1, 3), dim3(256), 0, stream>>>(hb, wb, b0, b1, b2, tgt, perm, cnt, hoff,
                                                     psum, tlog);
  k_final<<<dim3(1), dim3(1024), 0, stream>>>(psum, tlog, out);
}